// Round 1
// 448.451 us; speedup vs baseline: 1.1365x; 1.1365x over previous
//
#include <hip/hip_runtime.h>
#include <cstdint>
#include <cstddef>

#define KIN 300
#define KPAD 320
#define HIDDEN 128
#define BSZ 256
#define TSZ 512

typedef __attribute__((ext_vector_type(8))) short short8;
typedef __attribute__((ext_vector_type(4))) float f32x4;

__device__ __forceinline__ short f2bf(float f) {
  uint32_t u = __builtin_bit_cast(uint32_t, f);
  u = (u + 0x7FFFu + ((u >> 16) & 1u)) >> 16;
  return (short)u;
}
__device__ __forceinline__ float bf2f(short s) {
  uint32_t u = ((uint32_t)(uint16_t)s) << 16;
  return __builtin_bit_cast(float, u);
}
__device__ __forceinline__ float bflo(uint32_t u) {
  return __builtin_bit_cast(float, u << 16);
}
__device__ __forceinline__ float bfhi(uint32_t u) {
  return __builtin_bit_cast(float, u & 0xFFFF0000u);
}
__device__ __forceinline__ uint32_t pack2bf(float a, float b) {
  return (uint32_t)(uint16_t)f2bf(a) | ((uint32_t)(uint16_t)f2bf(b) << 16);
}
// tanh(x) = 1 - 2/(exp2(x*2*log2e)+1); exact at +/-1 extremes, 5 VALU inst.
__device__ __forceinline__ float tanhf_fast(float v) {
  const float e = __builtin_amdgcn_exp2f(v * 2.88539008177793f);
  return fmaf(-2.0f, __builtin_amdgcn_rcpf(e + 1.0f), 1.0f);
}
// Barrier that waits LDS ops but leaves global/DMA (vmcnt) in flight.
__device__ __forceinline__ void barrier_lds() {
  asm volatile("s_waitcnt lgkmcnt(0)\n\ts_barrier" ::: "memory");
}
__device__ __forceinline__ void barrier_all() {
  asm volatile("s_waitcnt vmcnt(0) lgkmcnt(0)\n\ts_barrier" ::: "memory");
}
// async 16B/lane global->LDS DMA: lds dst = uniform base + lane*16
__device__ __forceinline__ void dma16(const short* g, short* l) {
  __builtin_amdgcn_global_load_lds(
      (const __attribute__((address_space(1))) void*)g,
      (__attribute__((address_space(3))) void*)l, 16, 0, 0);
}

// ---------------- Phase 0: W_ih -> bf16, K zero-padded to 320 --------------
__global__ __launch_bounds__(256) void wcvt_bf16(const float* __restrict__ W,
                                                 short* __restrict__ W16) {
  const int i = blockIdx.x * 256 + threadIdx.x;
  if (i >= HIDDEN * KPAD) return;
  const int n = i / KPAD, k = i % KPAD;
  W16[i] = (k < KIN) ? f2bf(W[n * KIN + k]) : (short)0;
}

// ---------------- Phase 1: xp = x @ W_ih^T + bias, DMA-native layout -------
// (unchanged, verified) Block = 16 batches x 4 timesteps = 64 rows; x row-tile
// staged in LDS ONCE (bf16, 42 KB) -> x read exactly 1x from HBM.
__global__ __launch_bounds__(256) void xp_gemm_mfma(
    const float* __restrict__ x, const short* __restrict__ W16,
    const float* __restrict__ b_ih, const float* __restrict__ b_hh,
    short* __restrict__ xp16) {
  __shared__ __align__(16) short As[64 * 328];  // 42 KB; reused as epilogue stage
  const int tid = threadIdx.x;
  const int lane = tid & 63, w = tid >> 6;
  const int q = lane >> 4, c = lane & 15;
  const int bg = blockIdx.x & 15, tc = blockIdx.x >> 4;
  const int b0 = bg * 16, t0 = tc * 4;

  // ---- stage x tile (64 rows x 300 K) as bf16, padded stride 328 ----
#pragma unroll
  for (int i = 0; i < 19; ++i) {
    const int f = tid + 256 * i;  // float4 index over 64*75
    if (f < 4800) {
      const int rr = f / 75;
      const int k4 = f - rr * 75;
      const int b_in = rr >> 2, t_loc = rr & 3;
      const float4 v = *(const float4*)(
          x + ((size_t)(b0 + b_in) * TSZ + t0 + t_loc) * KIN + k4 * 4);
      uint2 pv;
      pv.x = pack2bf(v.x, v.y);
      pv.y = pack2bf(v.z, v.w);
      *(uint2*)&As[rr * 328 + k4 * 4] = pv;
    }
  }
  if (tid < 64) {  // zero-pad k = 300..319
    const uint2 z = {0u, 0u};
#pragma unroll
    for (int j = 0; j < 5; ++j) *(uint2*)&As[tid * 328 + 300 + j * 4] = z;
  }
  __syncthreads();

  // wave w owns h-tiles {2w, 2w+1} x all 4 row-tiles
  f32x4 acc[2][4];
#pragma unroll
  for (int ht = 0; ht < 2; ++ht)
#pragma unroll
    for (int rt = 0; rt < 4; ++rt) acc[ht][rt] = (f32x4){0.f, 0.f, 0.f, 0.f};

  // A-frags (W16, L2-resident): lane (q,c) -> A[m=c][k=q*8+j]
  const short* wp0 = W16 + (size_t)((2 * w + 0) * 16 + c) * KPAD + q * 8;
  const short* wp1 = W16 + (size_t)((2 * w + 1) * 16 + c) * KPAD + q * 8;
  short8 af[2][2];
  af[0][0] = *(const short8*)(wp0);
  af[0][1] = *(const short8*)(wp1);
#pragma unroll
  for (int kc = 0; kc < 10; ++kc) {
    const int cur = kc & 1;
    if (kc < 9) {
      af[cur ^ 1][0] = *(const short8*)(wp0 + (kc + 1) * 32);
      af[cur ^ 1][1] = *(const short8*)(wp1 + (kc + 1) * 32);
    }
    short8 bq[4];
#pragma unroll
    for (int rt = 0; rt < 4; ++rt)
      bq[rt] = *(const short8*)&As[(rt * 16 + c) * 328 + kc * 32 + q * 8];
#pragma unroll
    for (int ht = 0; ht < 2; ++ht)
#pragma unroll
      for (int rt = 0; rt < 4; ++rt)
        acc[ht][rt] = __builtin_amdgcn_mfma_f32_16x16x32_bf16(
            af[cur][ht], bq[rt], acc[ht][rt], 0, 0, 0);
  }
  __syncthreads();  // all B-frag reads done; As becomes the stage buffer

  // ---- epilogue: bias, pack, LDS transpose to [t][g][b] (padded) ----
  float4 bsum[2];
#pragma unroll
  for (int ht = 0; ht < 2; ++ht) {
    const int h0 = (2 * w + ht) * 16 + q * 4;
    const float4 bi = *(const float4*)(b_ih + h0);
    const float4 bh = *(const float4*)(b_hh + h0);
    bsum[ht] = make_float4(bi.x + bh.x, bi.y + bh.y, bi.z + bh.z, bi.w + bh.w);
  }
  // stage layout: t stride 2312, g stride 72, b_in stride 4 (shorts)
#pragma unroll
  for (int ht = 0; ht < 2; ++ht) {
    const int g = (2 * w + ht) * 4 + q;
#pragma unroll
    for (int rt = 0; rt < 4; ++rt) {
      const int b_in = rt * 4 + (c >> 2);
      const int t_loc = c & 3;
      uint2 pv;
      pv.x = pack2bf(acc[ht][rt][0] + bsum[ht].x, acc[ht][rt][1] + bsum[ht].y);
      pv.y = pack2bf(acc[ht][rt][2] + bsum[ht].z, acc[ht][rt][3] + bsum[ht].w);
      *(uint2*)&As[t_loc * 2312 + g * 72 + b_in * 4] = pv;
    }
  }
  __syncthreads();
  // ---- coalesced copy-out: per t_loc a dense 4 KB region ----
#pragma unroll
  for (int i = 0; i < 4; ++i) {
    const int4 vv =
        *(const int4*)&As[i * 2312 + (tid >> 3) * 72 + (tid & 7) * 8];
    *(int4*)(xp16 + ((size_t)(t0 + i) * 16 + bg) * 2048 + tid * 8) = vv;
  }
}

// ---------------- Phase 2: MFMA-batched scan + fused FC --------------------
// NEW: 16 blocks x 512 threads (8 waves). H split across 8 waves (M=16 each)
// instead of 4 (M=32): per-wave serial work per step halves, and the CU gets
// 2 waves/SIMD so ds_read / MFMA / trans latencies hide each other.
// Per step per wave: 4 ds_read_b128 (full h as B-frag), 4 INDEPENDENT MFMAs
// (one per K-chunk, separate accumulators, tree-add -> no dependent MFMA
// chain), 4 tanh, 1 ds_write_b64, barrier. xp values for the whole 8-step
// chunk are preloaded into registers right after the chunk barrier (xs is
// double-buffered and h-independent), removing the per-step xs read.
__global__ __launch_bounds__(512, 2) void rnn_scan_dma(
    const short* __restrict__ xp16, const float* __restrict__ Whh,
    const float* __restrict__ fc_w, const float* __restrict__ fc_b,
    float* __restrict__ out) {
  __shared__ __align__(16) short xs[2][8][2048];  // 64 KB
  __shared__ __align__(16) short ht[2][16][136];  // 8.5 KB
  const int tid = threadIdx.x;
  const int lane = tid & 63, w = tid >> 6;      // w = 0..7
  const int q = lane >> 4, c = lane & 15;
  const int bg = blockIdx.x;

  // W_hh A-frags: wave w owns h-out rows [16w, 16w+16); one frag per K-chunk.
  short8 aw[4];
#pragma unroll
  for (int kc = 0; kc < 4; ++kc) {
    const float* src = Whh + (size_t)(w * 16 + c) * HIDDEN + kc * 32 + q * 8;
    const float4 v0 = *(const float4*)(src);
    const float4 v1 = *(const float4*)(src + 4);
    short8 t;
    t[0] = f2bf(v0.x); t[1] = f2bf(v0.y); t[2] = f2bf(v0.z); t[3] = f2bf(v0.w);
    t[4] = f2bf(v1.x); t[5] = f2bf(v1.y); t[6] = f2bf(v1.z); t[7] = f2bf(v1.w);
    aw[kc] = t;
  }

  // h0 = 0
  {
    uint32_t* z = (uint32_t*)&ht[0][0][0];
    for (int i = tid; i < 1088; i += 512) z[i] = 0;
  }

  // DMA issue: wave w covers chunk-step s = w, 4 x 1KB insts
#define ISSUE_CHUNK(CH, BUF)                                                  \
  {                                                                           \
    const short* srcb =                                                       \
        xp16 + ((size_t)((CH)*8 + w) * 16 + bg) * 2048 + lane * 8;            \
    _Pragma("unroll") for (int j = 0; j < 4; ++j)                             \
        dma16(srcb + j * 512, &xs[BUF][w][j * 512]);                          \
  }

  ISSUE_CHUNK(0, 0)
  barrier_all();  // chunk-0 DMA landed; ht zero + everyone ready

  const int gx = (w * 4 + q) * 64 + c * 4;  // xs offset: h-group w*4+q, batch c
  const int hb = w * 16 + q * 4;            // output h-base for this lane
  const f32x4 zero4 = {0.f, 0.f, 0.f, 0.f};

  for (int cc = 0; cc < 64; ++cc) {
    const int buf = cc & 1;
    if (cc + 1 < 64) ISSUE_CHUNK(cc + 1, buf ^ 1)
    // preload the whole chunk's xp for this lane (h-independent, dbuf'd)
    uint2 us[8];
#pragma unroll
    for (int s = 0; s < 8; ++s) us[s] = *(const uint2*)&xs[buf][s][gx];
#pragma unroll
    for (int s = 0; s < 8; ++s) {
      const int rb = s & 1;  // global t = cc*8+s; cc even so parity = s&1
      const short8 bh0 = *(const short8*)&ht[rb][c][0 + q * 8];
      const short8 bh1 = *(const short8*)&ht[rb][c][32 + q * 8];
      const short8 bh2 = *(const short8*)&ht[rb][c][64 + q * 8];
      const short8 bh3 = *(const short8*)&ht[rb][c][96 + q * 8];
      f32x4 a0 = {bflo(us[s].x), bfhi(us[s].x), bflo(us[s].y), bfhi(us[s].y)};
      f32x4 a1 = zero4, a2 = zero4, a3 = zero4;
      a0 = __builtin_amdgcn_mfma_f32_16x16x32_bf16(aw[0], bh0, a0, 0, 0, 0);
      a1 = __builtin_amdgcn_mfma_f32_16x16x32_bf16(aw[1], bh1, a1, 0, 0, 0);
      a2 = __builtin_amdgcn_mfma_f32_16x16x32_bf16(aw[2], bh2, a2, 0, 0, 0);
      a3 = __builtin_amdgcn_mfma_f32_16x16x32_bf16(aw[3], bh3, a3, 0, 0, 0);
      const f32x4 s0 = (a0 + a1) + (a2 + a3);
      uint2 w0;
      w0.x = pack2bf(tanhf_fast(s0[0]), tanhf_fast(s0[1]));
      w0.y = pack2bf(tanhf_fast(s0[2]), tanhf_fast(s0[3]));
      *(uint2*)&ht[rb ^ 1][c][hb] = w0;
      barrier_lds();
    }
    barrier_all();  // next chunk's DMA (issued ~8 steps ago) must be landed
  }
#undef ISSUE_CHUNK

  // h_last in ht[0] (t=511 wrote rb^1 = 0). FC: 32 outputs/block.
  if (tid < 32) {
    const int bi = tid >> 1, cls = tid & 1;
    float s = fc_b[cls];
    const float* fw = fc_w + cls * HIDDEN;
#pragma unroll 8
    for (int k = 0; k < HIDDEN; k += 4) {
      s = fmaf(bf2f(ht[0][bi][k + 0]), fw[k + 0], s);
      s = fmaf(bf2f(ht[0][bi][k + 1]), fw[k + 1], s);
      s = fmaf(bf2f(ht[0][bi][k + 2]), fw[k + 2], s);
      s = fmaf(bf2f(ht[0][bi][k + 3]), fw[k + 3], s);
    }
    out[(bg * 16 + bi) * 2 + cls] = s;
  }
}

extern "C" void kernel_launch(void* const* d_in, const int* in_sizes, int n_in,
                              void* d_out, int out_size, void* d_ws, size_t ws_size,
                              hipStream_t stream) {
  const float* x    = (const float*)d_in[0];
  const float* W_ih = (const float*)d_in[1];
  const float* W_hh = (const float*)d_in[2];
  const float* b_ih = (const float*)d_in[3];
  const float* b_hh = (const float*)d_in[4];
  const float* fc_w = (const float*)d_in[5];
  const float* fc_b = (const float*)d_in[6];
  short* xp16 = (short*)d_ws;                         // 32 MiB bf16 [T][16bg][2048]
  short* W16  = (short*)((char*)d_ws + (33u << 20));  // 80 KB bf16 [128][320]
  float* out  = (float*)d_out;

  wcvt_bf16<<<(HIDDEN * KPAD + 255) / 256, 256, 0, stream>>>(W_ih, W16);
  xp_gemm_mfma<<<16 * (TSZ / 4), 256, 0, stream>>>(x, W16, b_ih, b_hh, xp16);
  rnn_scan_dma<<<16, 512, 0, stream>>>(xp16, W_hh, fc_w, fc_b, out);
}

// Round 2
// 439.277 us; speedup vs baseline: 1.1602x; 1.0209x over previous
//
#include <hip/hip_runtime.h>
#include <cstdint>
#include <cstddef>

#define KIN 300
#define KPAD 320
#define HIDDEN 128
#define BSZ 256
#define TSZ 512

typedef __attribute__((ext_vector_type(8))) short short8;
typedef __attribute__((ext_vector_type(4))) short s16x4;
typedef __attribute__((ext_vector_type(4))) float f32x4;

__device__ __forceinline__ short f2bf(float f) {
  uint32_t u = __builtin_bit_cast(uint32_t, f);
  u = (u + 0x7FFFu + ((u >> 16) & 1u)) >> 16;
  return (short)u;
}
__device__ __forceinline__ float bf2f(short s) {
  uint32_t u = ((uint32_t)(uint16_t)s) << 16;
  return __builtin_bit_cast(float, u);
}
__device__ __forceinline__ float bflo(uint32_t u) {
  return __builtin_bit_cast(float, u << 16);
}
__device__ __forceinline__ float bfhi(uint32_t u) {
  return __builtin_bit_cast(float, u & 0xFFFF0000u);
}
// HW packed f32->bf16 RNE convert: lo = bf16(a), hi = bf16(b). 1 inst vs ~10.
__device__ __forceinline__ uint32_t pack2bf(float a, float b) {
  uint32_t r;
  asm("v_cvt_pk_bf16_f32 %0, %1, %2" : "=v"(r) : "v"(a), "v"(b));
  return r;
}
// tanh(x) = 1 - 2/(exp2(x*2*log2e)+1); exact at +/-1 extremes, 5 VALU inst.
__device__ __forceinline__ float tanhf_fast(float v) {
  const float e = __builtin_amdgcn_exp2f(v * 2.88539008177793f);
  return fmaf(-2.0f, __builtin_amdgcn_rcpf(e + 1.0f), 1.0f);
}
// Barrier that waits LDS ops but leaves global/DMA (vmcnt) in flight.
__device__ __forceinline__ void barrier_lds() {
  asm volatile("s_waitcnt lgkmcnt(0)\n\ts_barrier" ::: "memory");
}
__device__ __forceinline__ void barrier_all() {
  asm volatile("s_waitcnt vmcnt(0) lgkmcnt(0)\n\ts_barrier" ::: "memory");
}
// async 16B/lane global->LDS DMA: lds dst = uniform base + lane*16
__device__ __forceinline__ void dma16(const short* g, short* l) {
  __builtin_amdgcn_global_load_lds(
      (const __attribute__((address_space(1))) void*)g,
      (__attribute__((address_space(3))) void*)l, 16, 0, 0);
}
// Load a bf16 MFMA fragment from the split ht layout: 8 values as two
// separated short4 groups (can't be merged into a conflicting b128).
__device__ __forceinline__ short8 ld_bh(const short* lo) {
  const s16x4 a = *(const s16x4*)lo;
  const s16x4 b = *(const s16x4*)(lo + 64);
  return __builtin_shufflevector(a, b, 0, 1, 2, 3, 4, 5, 6, 7);
}

// ---------------- Phase 0: W_ih -> bf16, K zero-padded to 320 --------------
__global__ __launch_bounds__(256) void wcvt_bf16(const float* __restrict__ W,
                                                 short* __restrict__ W16) {
  const int i = blockIdx.x * 256 + threadIdx.x;
  if (i >= HIDDEN * KPAD) return;
  const int n = i / KPAD, k = i % KPAD;
  W16[i] = (k < KIN) ? f2bf(W[n * KIN + k]) : (short)0;
}

// ---------------- Phase 1: xp = x @ W_ih^T + bias, DMA-native layout -------
// Block = 16 batches x 4 timesteps = 64 rows; x row-tile staged in LDS ONCE
// (bf16, 42 KB) -> x read exactly 1x from HBM.
__global__ __launch_bounds__(256) void xp_gemm_mfma(
    const float* __restrict__ x, const short* __restrict__ W16,
    const float* __restrict__ b_ih, const float* __restrict__ b_hh,
    short* __restrict__ xp16) {
  __shared__ __align__(16) short As[64 * 328];  // 42 KB; reused as epilogue stage
  const int tid = threadIdx.x;
  const int lane = tid & 63, w = tid >> 6;
  const int q = lane >> 4, c = lane & 15;
  const int bg = blockIdx.x & 15, tc = blockIdx.x >> 4;
  const int b0 = bg * 16, t0 = tc * 4;

  // ---- stage x tile (64 rows x 300 K) as bf16, padded stride 328 ----
#pragma unroll
  for (int i = 0; i < 19; ++i) {
    const int f = tid + 256 * i;  // float4 index over 64*75
    if (f < 4800) {
      const int rr = f / 75;
      const int k4 = f - rr * 75;
      const int b_in = rr >> 2, t_loc = rr & 3;
      const float4 v = *(const float4*)(
          x + ((size_t)(b0 + b_in) * TSZ + t0 + t_loc) * KIN + k4 * 4);
      uint2 pv;
      pv.x = pack2bf(v.x, v.y);
      pv.y = pack2bf(v.z, v.w);
      *(uint2*)&As[rr * 328 + k4 * 4] = pv;
    }
  }
  if (tid < 64) {  // zero-pad k = 300..319
    const uint2 z = {0u, 0u};
#pragma unroll
    for (int j = 0; j < 5; ++j) *(uint2*)&As[tid * 328 + 300 + j * 4] = z;
  }
  __syncthreads();

  // wave w owns h-tiles {2w, 2w+1} x all 4 row-tiles
  f32x4 acc[2][4];
#pragma unroll
  for (int ht = 0; ht < 2; ++ht)
#pragma unroll
    for (int rt = 0; rt < 4; ++rt) acc[ht][rt] = (f32x4){0.f, 0.f, 0.f, 0.f};

  // A-frags (W16, L2-resident): lane (q,c) -> A[m=c][k=q*8+j]
  const short* wp0 = W16 + (size_t)((2 * w + 0) * 16 + c) * KPAD + q * 8;
  const short* wp1 = W16 + (size_t)((2 * w + 1) * 16 + c) * KPAD + q * 8;
  short8 af[2][2];
  af[0][0] = *(const short8*)(wp0);
  af[0][1] = *(const short8*)(wp1);
#pragma unroll
  for (int kc = 0; kc < 10; ++kc) {
    const int cur = kc & 1;
    if (kc < 9) {
      af[cur ^ 1][0] = *(const short8*)(wp0 + (kc + 1) * 32);
      af[cur ^ 1][1] = *(const short8*)(wp1 + (kc + 1) * 32);
    }
    short8 bq[4];
#pragma unroll
    for (int rt = 0; rt < 4; ++rt)
      bq[rt] = *(const short8*)&As[(rt * 16 + c) * 328 + kc * 32 + q * 8];
#pragma unroll
    for (int ht = 0; ht < 2; ++ht)
#pragma unroll
      for (int rt = 0; rt < 4; ++rt)
        acc[ht][rt] = __builtin_amdgcn_mfma_f32_16x16x32_bf16(
            af[cur][ht], bq[rt], acc[ht][rt], 0, 0, 0);
  }
  __syncthreads();  // all B-frag reads done; As becomes the stage buffer

  // ---- epilogue: bias, pack, LDS transpose to [t][g][b] (padded) ----
  float4 bsum[2];
#pragma unroll
  for (int ht = 0; ht < 2; ++ht) {
    const int h0 = (2 * w + ht) * 16 + q * 4;
    const float4 bi = *(const float4*)(b_ih + h0);
    const float4 bh = *(const float4*)(b_hh + h0);
    bsum[ht] = make_float4(bi.x + bh.x, bi.y + bh.y, bi.z + bh.z, bi.w + bh.w);
  }
  // stage layout: t stride 2312, g stride 72, b_in stride 4 (shorts)
#pragma unroll
  for (int ht = 0; ht < 2; ++ht) {
    const int g = (2 * w + ht) * 4 + q;
#pragma unroll
    for (int rt = 0; rt < 4; ++rt) {
      const int b_in = rt * 4 + (c >> 2);
      const int t_loc = c & 3;
      uint2 pv;
      pv.x = pack2bf(acc[ht][rt][0] + bsum[ht].x, acc[ht][rt][1] + bsum[ht].y);
      pv.y = pack2bf(acc[ht][rt][2] + bsum[ht].z, acc[ht][rt][3] + bsum[ht].w);
      *(uint2*)&As[t_loc * 2312 + g * 72 + b_in * 4] = pv;
    }
  }
  __syncthreads();
  // ---- coalesced copy-out: per t_loc a dense 4 KB region ----
#pragma unroll
  for (int i = 0; i < 4; ++i) {
    const int4 vv =
        *(const int4*)&As[i * 2312 + (tid >> 3) * 72 + (tid & 7) * 8];
    *(int4*)(xp16 + ((size_t)(t0 + i) * 16 + bg) * 2048 + tid * 8) = vv;
  }
}

// ---------------- Phase 2: MFMA-batched scan + fused FC --------------------
// 16 blocks x 512 threads (8 waves), wave w owns h-out rows [16w,16w+16).
// NEW vs round 1:
//  - ht rows use stride 132 shorts (264 B = 66 dw, +/-2 mod 32) and the
//    8-value k-fragment is SPLIT into two 4-short groups at cols g*4 and
//    64+g*4: each 16-lane quarter-wave's ds_read_b64 covers all 32 banks
//    exactly once -> conflict-free h broadcast (was 2-way replay on every
//    b128: ~160 extra cyc/step/CU).
//  - pack via v_cvt_pk_bf16_f32 (2 inst vs ~20/lane/step).
//  - MFMA as two dependent chains of 2 (one f32x4 add instead of three).
__global__ __launch_bounds__(512, 2) void rnn_scan_dma(
    const short* __restrict__ xp16, const float* __restrict__ Whh,
    const float* __restrict__ fc_w, const float* __restrict__ fc_b,
    float* __restrict__ out) {
  __shared__ __align__(16) short xs[2][8][2048];  // 64 KB
  __shared__ __align__(16) short ht[2][16][132];  // 8.25 KB, split-col layout
  const int tid = threadIdx.x;
  const int lane = tid & 63, w = tid >> 6;      // w = 0..7
  const int q = lane >> 4, c = lane & 15;
  const int bg = blockIdx.x;

  // W_hh A-frags: wave w owns h-out rows [16w, 16w+16); one frag per K-chunk.
  short8 aw[4];
#pragma unroll
  for (int kc = 0; kc < 4; ++kc) {
    const float* src = Whh + (size_t)(w * 16 + c) * HIDDEN + kc * 32 + q * 8;
    const float4 v0 = *(const float4*)(src);
    const float4 v1 = *(const float4*)(src + 4);
    short8 t;
    t[0] = f2bf(v0.x); t[1] = f2bf(v0.y); t[2] = f2bf(v0.z); t[3] = f2bf(v0.w);
    t[4] = f2bf(v1.x); t[5] = f2bf(v1.y); t[6] = f2bf(v1.z); t[7] = f2bf(v1.w);
    aw[kc] = t;
  }

  // h0 = 0
  {
    uint32_t* z = (uint32_t*)&ht[0][0][0];
    for (int i = tid; i < 2112; i += 512) z[i] = 0;
  }

  // DMA issue: wave w covers chunk-step s = w, 4 x 1KB insts
#define ISSUE_CHUNK(CH, BUF)                                                  \
  {                                                                           \
    const short* srcb =                                                       \
        xp16 + ((size_t)((CH)*8 + w) * 16 + bg) * 2048 + lane * 8;            \
    _Pragma("unroll") for (int j = 0; j < 4; ++j)                             \
        dma16(srcb + j * 512, &xs[BUF][w][j * 512]);                          \
  }

  ISSUE_CHUNK(0, 0)
  barrier_all();  // chunk-0 DMA landed; ht zero + everyone ready

  const int gx = (w * 4 + q) * 64 + c * 4;  // xs offset: h-group w*4+q, batch c
  // split-layout write base: rows k = w*16+q*4+{0..3} -> 8-group 2w+(q>>1),
  // j = (q&1)*4+r -> col = (q&1)*64 + (2w+(q>>1))*4 + r
  const int cb = (q & 1) * 64 + (2 * w + (q >> 1)) * 4;
  // split-layout read base for chunk kc: cols 16*kc+4*q (+64 for j>=4)
  const short* bhp0 = &ht[0][c][4 * q];
  const short* bhp1 = &ht[1][c][4 * q];

  for (int cc = 0; cc < 64; ++cc) {
    const int buf = cc & 1;
    if (cc + 1 < 64) ISSUE_CHUNK(cc + 1, buf ^ 1)
    // preload the whole chunk's xp for this lane (h-independent, dbuf'd)
    uint2 us[8];
#pragma unroll
    for (int s = 0; s < 8; ++s) us[s] = *(const uint2*)&xs[buf][s][gx];
#pragma unroll
    for (int s = 0; s < 8; ++s) {
      const int rb = s & 1;  // global t = cc*8+s; cc even so parity = s&1
      const short* bp = rb ? bhp1 : bhp0;
      const short8 bh0 = ld_bh(bp + 0);
      const short8 bh1 = ld_bh(bp + 16);
      const short8 bh2 = ld_bh(bp + 32);
      const short8 bh3 = ld_bh(bp + 48);
      f32x4 a0 = {bflo(us[s].x), bfhi(us[s].x), bflo(us[s].y), bfhi(us[s].y)};
      f32x4 a2 = {0.f, 0.f, 0.f, 0.f};
      a0 = __builtin_amdgcn_mfma_f32_16x16x32_bf16(aw[0], bh0, a0, 0, 0, 0);
      a2 = __builtin_amdgcn_mfma_f32_16x16x32_bf16(aw[2], bh2, a2, 0, 0, 0);
      a0 = __builtin_amdgcn_mfma_f32_16x16x32_bf16(aw[1], bh1, a0, 0, 0, 0);
      a2 = __builtin_amdgcn_mfma_f32_16x16x32_bf16(aw[3], bh3, a2, 0, 0, 0);
      const f32x4 s0 = a0 + a2;
      uint2 w0;
      w0.x = pack2bf(tanhf_fast(s0[0]), tanhf_fast(s0[1]));
      w0.y = pack2bf(tanhf_fast(s0[2]), tanhf_fast(s0[3]));
      *(uint2*)&ht[rb ^ 1][c][cb] = w0;
      barrier_lds();
    }
    barrier_all();  // next chunk's DMA (issued ~8 steps ago) must be landed
  }
#undef ISSUE_CHUNK

  // h_last in ht[0] (t=511 wrote rb^1 = 0). FC: 32 outputs/block.
  // Split layout: k = g8*8 + j; j<4 at col g8*4+j, j>=4 at col 64+g8*4+(j-4).
  if (tid < 32) {
    const int bi = tid >> 1, cls = tid & 1;
    float s = fc_b[cls];
    const float* fw = fc_w + cls * HIDDEN;
#pragma unroll 4
    for (int g8 = 0; g8 < 16; ++g8) {
#pragma unroll
      for (int j = 0; j < 4; ++j) {
        s = fmaf(bf2f(ht[0][bi][g8 * 4 + j]), fw[g8 * 8 + j], s);
        s = fmaf(bf2f(ht[0][bi][64 + g8 * 4 + j]), fw[g8 * 8 + 4 + j], s);
      }
    }
    out[(bg * 16 + bi) * 2 + cls] = s;
  }
}

extern "C" void kernel_launch(void* const* d_in, const int* in_sizes, int n_in,
                              void* d_out, int out_size, void* d_ws, size_t ws_size,
                              hipStream_t stream) {
  const float* x    = (const float*)d_in[0];
  const float* W_ih = (const float*)d_in[1];
  const float* W_hh = (const float*)d_in[2];
  const float* b_ih = (const float*)d_in[3];
  const float* b_hh = (const float*)d_in[4];
  const float* fc_w = (const float*)d_in[5];
  const float* fc_b = (const float*)d_in[6];
  short* xp16 = (short*)d_ws;                         // 32 MiB bf16 [T][16bg][2048]
  short* W16  = (short*)((char*)d_ws + (33u << 20));  // 80 KB bf16 [128][320]
  float* out  = (float*)d_out;

  wcvt_bf16<<<(HIDDEN * KPAD + 255) / 256, 256, 0, stream>>>(W_ih, W16);
  xp_gemm_mfma<<<16 * (TSZ / 4), 256, 0, stream>>>(x, W16, b_ih, b_hh, xp16);
  rnn_scan_dma<<<16, 512, 0, stream>>>(xp16, W_hh, fc_w, fc_b, out);
}